// Round 7
// baseline (1435.243 us; speedup 1.0000x reference)
//
#include <hip/hip_runtime.h>

#define HD 100
#define NF 16
#define EF 8
#define NN 50000
#define NE 400000

typedef __attribute__((ext_vector_type(8))) short bf16x8;
typedef __attribute__((ext_vector_type(4))) float f32x4;

__device__ __forceinline__ float frelu(float v) { return v > 0.f ? v : 0.f; }
__device__ __forceinline__ unsigned short f2bf(float f) {
  unsigned int u = __float_as_uint(f);
  unsigned int r = (u + 0x7FFF + ((u >> 16) & 1)) >> 16;   // RNE
  return (unsigned short)r;
}
// XOR-swizzle: spread bank-aligned rows across 16B slots (G4 / T2)
__device__ __forceinline__ int SWZ(int row, int byte) { return byte ^ ((row & 7) << 4); }
__device__ __forceinline__ float4 L4(const float* p) { return *(const float4*)p; }
__device__ __forceinline__ bf16x8 cvt8(float4 a, float4 b) {
  bf16x8 r;
  r[0] = (short)f2bf(a.x); r[1] = (short)f2bf(a.y);
  r[2] = (short)f2bf(a.z); r[3] = (short)f2bf(a.w);
  r[4] = (short)f2bf(b.x); r[5] = (short)f2bf(b.y);
  r[6] = (short)f2bf(b.z); r[7] = (short)f2bf(b.w);
  return r;
}

// ---------------- weight pre-pack: W[K][N] fp32 -> frag-linear bf16 ----------------
__global__ __launch_bounds__(256) void k_pack(const float* __restrict__ W,
    unsigned short* __restrict__ out, int K, int N, int KS, int NT) {
  int t = blockIdx.x * 256 + threadIdx.x;
  if (t >= KS * NT * 64) return;
  int lane = t & 63, nt = (t >> 6) % NT, ks = (t >> 6) / NT;
  int kb = ks * 32 + (lane >> 4) * 8, n = nt * 16 + (lane & 15);
  unsigned short v[8];
  #pragma unroll
  for (int j = 0; j < 8; ++j) {
    int k = kb + j;
    float f = (k < K && n < N) ? W[(size_t)k * N + n] : 0.f;
    v[j] = f2bf(f);
  }
  uint4 o4;
  o4.x = (unsigned)v[0] | ((unsigned)v[1] << 16);
  o4.y = (unsigned)v[2] | ((unsigned)v[3] << 16);
  o4.z = (unsigned)v[4] | ((unsigned)v[5] << 16);
  o4.w = (unsigned)v[6] | ((unsigned)v[7] << 16);
  *(uint4*)&out[(size_t)t * 8] = o4;
}

__global__ __launch_bounds__(256) void k_node_embed(const float* __restrict__ x,
    const float* __restrict__ w, const float* __restrict__ b, float* __restrict__ h) {
  int t = blockIdx.x * 256 + threadIdx.x;
  int n = t / HD, o = t % HD;
  if (n >= NN) return;
  float acc = b[o];
  #pragma unroll
  for (int k = 0; k < NF; ++k) acc = fmaf(x[n * NF + k], w[k * HD + o], acc);
  h[(size_t)n * HD + o] = acc;
}

// e stored in PERMUTED (dst-sorted) layout; float4 outputs, LDS-staged weights
__global__ __launch_bounds__(256) void k_edge_embed_perm(const float* __restrict__ ea,
    const int* __restrict__ eids, const float* __restrict__ w, const float* __restrict__ b,
    float* __restrict__ e) {
  __shared__ float ws_[EF * HD];
  __shared__ float bs_[HD];
  int tid = threadIdx.x;
  for (int i = tid; i < EF * HD; i += 256) ws_[i] = w[i];
  for (int i = tid; i < HD; i += 256) bs_[i] = b[i];
  __syncthreads();
  long long t = (long long)blockIdx.x * 256 + tid;
  int p = (int)(t / 25), c4 = (int)(t % 25);
  if (p >= NE) return;
  int eid = eids[p];
  const float* ap = ea + (size_t)eid * EF;
  float4 a0 = L4(ap), a1 = L4(ap + 4);
  float av[8] = {a0.x, a0.y, a0.z, a0.w, a1.x, a1.y, a1.z, a1.w};
  int c0 = c4 * 4;
  float o0 = bs_[c0], o1 = bs_[c0 + 1], o2 = bs_[c0 + 2], o3 = bs_[c0 + 3];
  #pragma unroll
  for (int k = 0; k < EF; ++k) {
    const float* wr = &ws_[k * HD + c0];
    o0 = fmaf(av[k], wr[0], o0); o1 = fmaf(av[k], wr[1], o1);
    o2 = fmaf(av[k], wr[2], o2); o3 = fmaf(av[k], wr[3], o3);
  }
  float4 o; o.x = o0; o.y = o1; o.z = o2; o.w = o3;
  ((float4*)e)[(size_t)p * 25 + c4] = o;
}

// ---------------- CSR build ----------------
__global__ __launch_bounds__(256) void k_hist(const int* __restrict__ dst, int* __restrict__ deg) {
  int eid = blockIdx.x * 256 + threadIdx.x;
  if (eid < NE) atomicAdd(&deg[dst[eid]], 1);
}
__global__ __launch_bounds__(256) void k_scan_part(const int* __restrict__ deg, int* __restrict__ part) {
  __shared__ int sm[256];
  int i = blockIdx.x * 256 + threadIdx.x;
  sm[threadIdx.x] = (i < NN) ? deg[i] : 0;
  __syncthreads();
  for (int s = 128; s > 0; s >>= 1) {
    if (threadIdx.x < s) sm[threadIdx.x] += sm[threadIdx.x + s];
    __syncthreads();
  }
  if (threadIdx.x == 0) part[blockIdx.x] = sm[0];
}
__global__ __launch_bounds__(256) void k_scan_top(int* __restrict__ part, int nb) {
  __shared__ int sm[256];
  int v = (threadIdx.x < nb) ? part[threadIdx.x] : 0;
  sm[threadIdx.x] = v;
  __syncthreads();
  for (int off = 1; off < 256; off <<= 1) {
    int t = (threadIdx.x >= (unsigned)off) ? sm[threadIdx.x - off] : 0;
    __syncthreads();
    sm[threadIdx.x] += t;
    __syncthreads();
  }
  if (threadIdx.x < nb) part[threadIdx.x] = sm[threadIdx.x] - v;  // exclusive
}
__global__ __launch_bounds__(256) void k_scan_fill(const int* __restrict__ deg,
    const int* __restrict__ part, int* __restrict__ rowptr) {
  __shared__ int sm[256];
  int i = blockIdx.x * 256 + threadIdx.x;
  int v = (i < NN) ? deg[i] : 0;
  sm[threadIdx.x] = v;
  __syncthreads();
  for (int off = 1; off < 256; off <<= 1) {
    int t = (threadIdx.x >= (unsigned)off) ? sm[threadIdx.x - off] : 0;
    __syncthreads();
    sm[threadIdx.x] += t;
    __syncthreads();
  }
  if (i <= NN) rowptr[i] = part[blockIdx.x] + sm[threadIdx.x] - v;
}
__global__ __launch_bounds__(256) void k_copy(const int* __restrict__ a, int* __restrict__ b) {
  int i = blockIdx.x * 256 + threadIdx.x;
  if (i < NN) b[i] = a[i];
}
__global__ __launch_bounds__(256) void k_fill(const int* __restrict__ dst,
    int* __restrict__ cursor, int* __restrict__ eids) {
  int eid = blockIdx.x * 256 + threadIdx.x;
  if (eid >= NE) return;
  int pos = atomicAdd(&cursor[dst[eid]], 1);
  eids[pos] = eid;
}

// ---------------- gather-sum agg ----------------
__global__ __launch_bounds__(256) void k_gather(const float* __restrict__ h,
    const float* __restrict__ e, const int* __restrict__ rowptr,
    const int* __restrict__ eids, const int* __restrict__ src, float* __restrict__ agg) {
  int slot = threadIdx.x >> 2, sub = threadIdx.x & 3;
  int n = blockIdx.x * 64 + slot;
  if (n >= NN) return;
  int r0 = rowptr[n], r1 = rowptr[n + 1];
  float4 acc[7];
  #pragma unroll
  for (int i = 0; i < 7; ++i) { acc[i].x = 0.f; acc[i].y = 0.f; acc[i].z = 0.f; acc[i].w = 0.f; }
  for (int p = r0; p < r1; ++p) {
    int s = src[eids[p]];
    const float4* hp = (const float4*)&h[(size_t)s * HD];
    const float4* ep = (const float4*)&e[(size_t)p * HD];
    #pragma unroll
    for (int i = 0; i < 7; ++i) {
      int c = sub + i * 4;
      if (c < 25) {
        float4 hv = hp[c], ev = ep[c];
        acc[i].x += frelu(hv.x + ev.x);
        acc[i].y += frelu(hv.y + ev.y);
        acc[i].z += frelu(hv.z + ev.z);
        acc[i].w += frelu(hv.w + ev.w);
      }
    }
  }
  float4* ap = (float4*)&agg[(size_t)n * HD];
  #pragma unroll
  for (int i = 0; i < 7; ++i) {
    int c = sub + i * 4;
    if (c < 25) ap[c] = acc[i];
  }
}

// fp32 node update (accuracy-critical path)
__global__ __launch_bounds__(256) void k_node_update(float* __restrict__ h,
    const float* __restrict__ agg,
    const float* __restrict__ w1, const float* __restrict__ b1,
    const float* __restrict__ w2, const float* __restrict__ b2,
    const float* __restrict__ gamma, const float* __restrict__ beta) {
  __shared__ float zs[64 * 101];
  int tid = threadIdx.x;
  int base = blockIdx.x * 64;
  for (int idx = tid; idx < 64 * HD; idx += 256) {
    int n = idx / HD, k = idx % HD;
    int gn = base + n; int cn = gn < NN ? gn : NN - 1;
    zs[n * 101 + k] = h[(size_t)cn * HD + k] + agg[(size_t)cn * HD + k];
  }
  __syncthreads();
  int el = tid & 63;
  int o0 = __builtin_amdgcn_readfirstlane((tid >> 6) * 25);
  float* row = &zs[el * 101];
  float acc[25];
  #pragma unroll
  for (int j = 0; j < 25; ++j) acc[j] = b1[o0 + j];
  for (int k = 0; k < HD; ++k) {
    float a = row[k];
    const float* wr = &w1[k * HD + o0];
    #pragma unroll
    for (int j = 0; j < 25; ++j) acc[j] = fmaf(a, wr[j], acc[j]);
  }
  __syncthreads();
  #pragma unroll
  for (int j = 0; j < 25; ++j) row[o0 + j] = frelu(acc[j]);
  __syncthreads();
  float acc2[25];
  #pragma unroll
  for (int j = 0; j < 25; ++j) acc2[j] = b2[o0 + j];
  for (int k = 0; k < HD; ++k) {
    float a = row[k];
    const float* wr = &w2[k * HD + o0];
    #pragma unroll
    for (int j = 0; j < 25; ++j) acc2[j] = fmaf(a, wr[j], acc2[j]);
  }
  int gn = base + el;
  if (gn < NN) {
    const float bninv = 0.99999500003749973f;  // 1/sqrt(1+1e-5)
    #pragma unroll
    for (int j = 0; j < 25; ++j) {
      int o = o0 + j;
      float bn = acc2[j] * (gamma[o] * bninv) + beta[o];
      h[(size_t)gn * HD + o] = (h[(size_t)gn * HD + o] + frelu(bn)) * 0.5f;
    }
  }
}

// ---------------- layer-1 MFMA edge update: register-A, e RMW from regs ----------------
__global__ __launch_bounds__(256, 3) void k_edge_mfma(
    const float* __restrict__ h, float* __restrict__ e,
    const int* __restrict__ eids, const int* __restrict__ src, const int* __restrict__ dst,
    const unsigned short* __restrict__ w1p, const float* __restrict__ b1,
    const unsigned short* __restrict__ w2p, const float* __restrict__ b2) {
  __shared__ __align__(16) char lds[31232];
  char* A2  = lds;                 // 16384: GEMM2 A (bf16 [64][128] swizzled)
  char* WBa = lds + 16384;         // 7168
  char* WBb = lds + 23552;         // 7168
  int* ss  = (int*)(lds + 30720);
  int* ds_ = (int*)(lds + 30976);
  int tid = threadIdx.x;
  int base = blockIdx.x * 64;
  if (tid < 64) { int eid = eids[base + tid]; ss[tid] = src[eid]; ds_[tid] = dst[eid]; }
  for (int c = tid; c < 448; c += 256)
    *(uint4*)(WBa + c * 16) = ((const uint4*)w1p)[c];
  __syncthreads();

  int lane = tid & 63, w = tid >> 6;
  int l15 = lane & 15, lq = lane >> 4;
  int arow = w * 16 + l15;
  const float* hs = h + (size_t)ss[arow] * HD;
  const float* hd = h + (size_t)ds_[arow] * HD;
  const float* ep = e + (size_t)(base + arow) * HD;
  float4 z4; z4.x = z4.y = z4.z = z4.w = 0.f;

  // A fragments in registers: af[ks] = bf16 of row elems k=ks*32+lq*8 .. +7
  bf16x8 af[10];
  af[0] = cvt8(L4(hs + lq * 8),      L4(hs + lq * 8 + 4));
  af[1] = cvt8(L4(hs + 32 + lq * 8), L4(hs + 36 + lq * 8));
  af[2] = cvt8(L4(hs + 64 + lq * 8), L4(hs + 68 + lq * 8));
  af[3] = (lq == 0) ? cvt8(L4(hs + 96), L4(hd))
                    : cvt8(L4(hd + lq * 8 - 4), L4(hd + lq * 8));
  af[4] = cvt8(L4(hd + 28 + lq * 8), L4(hd + 32 + lq * 8));
  af[5] = cvt8(L4(hd + 60 + lq * 8), L4(hd + 64 + lq * 8));
  af[6] = (lq == 0) ? cvt8(L4(hd + 92), L4(hd + 96))
                    : cvt8(L4(ep + lq * 8 - 8), L4(ep + lq * 8 - 4));
  af[7] = cvt8(L4(ep + 24 + lq * 8), L4(ep + 28 + lq * 8));
  af[8] = cvt8(L4(ep + 56 + lq * 8), L4(ep + 60 + lq * 8));
  af[9] = (lq == 0) ? cvt8(L4(ep + 88), L4(ep + 92))
        : (lq == 1) ? cvt8(L4(ep + 96), z4)
                    : cvt8(z4, z4);

  f32x4 zero = {0.f, 0.f, 0.f, 0.f};
  f32x4 acc[7];
  #pragma unroll
  for (int nt = 0; nt < 7; ++nt) acc[nt] = zero;
  #pragma unroll
  for (int ks = 0; ks < 10; ++ks) {
    char* rb = (ks & 1) ? WBb : WBa;
    char* wb = (ks & 1) ? WBa : WBb;
    uint4 st0, st1;
    if (ks < 9) {
      const uint4* wp = (const uint4*)w1p + (size_t)(ks + 1) * 448;
      st0 = wp[tid];
      if (tid < 192) st1 = wp[256 + tid];
    }
    #pragma unroll
    for (int nt = 0; nt < 7; ++nt) {
      bf16x8 b = *(const bf16x8*)(rb + (nt * 64 + lane) * 16);
      acc[nt] = __builtin_amdgcn_mfma_f32_16x16x32_bf16(af[ks], b, acc[nt], 0, 0, 0);
    }
    if (ks < 9) {
      *(uint4*)(wb + tid * 16) = st0;
      if (tid < 192) *(uint4*)(wb + (256 + tid) * 16) = st1;
    }
    __syncthreads();
  }

  // epilogue1: relu(C1+b1) -> bf16 A2 [64][128] stride 256 (swizzled)
  #pragma unroll
  for (int nt = 0; nt < 7; ++nt) {
    int o = nt * 16 + l15;
    float bias = (o < HD) ? b1[o] : 0.f;
    #pragma unroll
    for (int i = 0; i < 4; ++i) {
      int r = w * 16 + lq * 4 + i;
      float v = acc[nt][i] + bias;
      v = (o < HD) ? frelu(v) : 0.f;
      *(unsigned short*)(A2 + SWZ(r, r * 256 + o * 2)) = f2bf(v);
    }
  }
  for (int idx = tid; idx < 64 * 8; idx += 256) {
    int r = idx / 8, c = idx % 8;
    *(unsigned int*)(A2 + SWZ(r, r * 256 + 224 + c * 4)) = 0;
  }
  for (int c = tid; c < 448; c += 256)
    *(uint4*)(WBa + c * 16) = ((const uint4*)w2p)[c];
  __syncthreads();

  f32x4 acc2[7];
  #pragma unroll
  for (int nt = 0; nt < 7; ++nt) acc2[nt] = zero;
  #pragma unroll
  for (int ks = 0; ks < 4; ++ks) {
    char* rb = (ks & 1) ? WBb : WBa;
    char* wb = (ks & 1) ? WBa : WBb;
    uint4 st0, st1;
    if (ks < 3) {
      const uint4* wp = (const uint4*)w2p + (size_t)(ks + 1) * 448;
      st0 = wp[tid];
      if (tid < 192) st1 = wp[256 + tid];
    }
    bf16x8 a = *(const bf16x8*)(A2 + SWZ(arow, arow * 256 + (ks * 32 + lq * 8) * 2));
    #pragma unroll
    for (int nt = 0; nt < 7; ++nt) {
      bf16x8 b = *(const bf16x8*)(rb + (nt * 64 + lane) * 16);
      acc2[nt] = __builtin_amdgcn_mfma_f32_16x16x32_bf16(a, b, acc2[nt], 0, 0, 0);
    }
    if (ks < 3) {
      *(uint4*)(wb + tid * 16) = st0;
      if (tid < 192) *(uint4*)(wb + (256 + tid) * 16) = st1;
    }
    __syncthreads();
  }
  // epilogue2: e += 0.5*(C2+b2) directly from C-layout regs (64B-coalesced per 16 lanes)
  #pragma unroll
  for (int nt = 0; nt < 7; ++nt) {
    int o = nt * 16 + l15;
    if (o < HD) {
      float bias = b2[o];
      #pragma unroll
      for (int i = 0; i < 4; ++i) {
        int r = w * 16 + lq * 4 + i;
        size_t p = (size_t)(base + r) * HD + o;
        e[p] = e[p] + 0.5f * (acc2[nt][i] + bias);
      }
    }
  }
}

// ------- layer-2 edge update FUSED with final MLP: register-A throughout -------
__global__ __launch_bounds__(256, 3) void k_edge_final_mfma(
    const float* __restrict__ h, const float* __restrict__ e,
    const int* __restrict__ eids, const int* __restrict__ src, const int* __restrict__ dst,
    const unsigned short* __restrict__ w1p, const float* __restrict__ b1,
    const unsigned short* __restrict__ w2p, const float* __restrict__ b2,
    const unsigned short* __restrict__ wf1p, const float* __restrict__ fb1,
    const float* __restrict__ fw2, const float* __restrict__ fb2,
    const float* __restrict__ fw3, const float* __restrict__ fb3,
    float* __restrict__ out) {
  __shared__ __align__(16) char lds[36704];
  char* A2  = lds;                      // 16384: GEMM2-A / e_new exchange / t fp32
  char* WBa = lds + 16384;              // 7168
  char* WBb = lds + 23552;              // 7168
  float* W2s = (float*)(lds + 30720);   // 1250
  float* b2s = (float*)(lds + 35720);   // 25
  float* W3s = (float*)(lds + 35820);   // 25
  float* b3s = (float*)(lds + 35920);   // 1
  int* es  = (int*)(lds + 35924);       // 64
  int* ss  = (int*)(lds + 36180);       // 64
  int* ds_ = (int*)(lds + 36436);       // 64
  int tid = threadIdx.x;
  int base = blockIdx.x * 64;
  if (tid < 64) { int eid = eids[base + tid]; es[tid] = eid; ss[tid] = src[eid]; ds_[tid] = dst[eid]; }
  for (int c = tid; c < 1250; c += 256) W2s[c] = fw2[c];
  if (tid < 25) { b2s[tid] = fb2[tid]; W3s[tid] = fw3[tid]; }
  if (tid == 0) b3s[0] = fb3[0];
  for (int c = tid; c < 448; c += 256)
    *(uint4*)(WBa + c * 16) = ((const uint4*)w1p)[c];
  __syncthreads();

  int lane = tid & 63, w = tid >> 6;
  int l15 = lane & 15, lq = lane >> 4;
  int arow = w * 16 + l15;
  const float* hs = h + (size_t)ss[arow] * HD;
  const float* hd = h + (size_t)ds_[arow] * HD;
  const float* ep = e + (size_t)(base + arow) * HD;
  float4 z4; z4.x = z4.y = z4.z = z4.w = 0.f;

  bf16x8 af[10];
  af[0] = cvt8(L4(hs + lq * 8),      L4(hs + lq * 8 + 4));
  af[1] = cvt8(L4(hs + 32 + lq * 8), L4(hs + 36 + lq * 8));
  af[2] = cvt8(L4(hs + 64 + lq * 8), L4(hs + 68 + lq * 8));
  af[3] = (lq == 0) ? cvt8(L4(hs + 96), L4(hd))
                    : cvt8(L4(hd + lq * 8 - 4), L4(hd + lq * 8));
  af[4] = cvt8(L4(hd + 28 + lq * 8), L4(hd + 32 + lq * 8));
  af[5] = cvt8(L4(hd + 60 + lq * 8), L4(hd + 64 + lq * 8));
  af[6] = (lq == 0) ? cvt8(L4(hd + 92), L4(hd + 96))
                    : cvt8(L4(ep + lq * 8 - 8), L4(ep + lq * 8 - 4));
  af[7] = cvt8(L4(ep + 24 + lq * 8), L4(ep + 28 + lq * 8));
  af[8] = cvt8(L4(ep + 56 + lq * 8), L4(ep + 60 + lq * 8));
  af[9] = (lq == 0) ? cvt8(L4(ep + 88), L4(ep + 92))
        : (lq == 1) ? cvt8(L4(ep + 96), z4)
                    : cvt8(z4, z4);

  f32x4 zero = {0.f, 0.f, 0.f, 0.f};
  // -------- GEMM1 --------
  f32x4 acc[7];
  #pragma unroll
  for (int nt = 0; nt < 7; ++nt) acc[nt] = zero;
  #pragma unroll
  for (int ks = 0; ks < 10; ++ks) {
    char* rb = (ks & 1) ? WBb : WBa;
    char* wb = (ks & 1) ? WBa : WBb;
    uint4 st0, st1;
    if (ks < 9) {
      const uint4* wp = (const uint4*)w1p + (size_t)(ks + 1) * 448;
      st0 = wp[tid];
      if (tid < 192) st1 = wp[256 + tid];
    }
    #pragma unroll
    for (int nt = 0; nt < 7; ++nt) {
      bf16x8 b = *(const bf16x8*)(rb + (nt * 64 + lane) * 16);
      acc[nt] = __builtin_amdgcn_mfma_f32_16x16x32_bf16(af[ks], b, acc[nt], 0, 0, 0);
    }
    if (ks < 9) {
      *(uint4*)(wb + tid * 16) = st0;
      if (tid < 192) *(uint4*)(wb + (256 + tid) * 16) = st1;
    }
    __syncthreads();
  }
  // epilogue1: relu(C1+b1) -> bf16 A2
  #pragma unroll
  for (int nt = 0; nt < 7; ++nt) {
    int o = nt * 16 + l15;
    float bias = (o < HD) ? b1[o] : 0.f;
    #pragma unroll
    for (int i = 0; i < 4; ++i) {
      int r = w * 16 + lq * 4 + i;
      float v = acc[nt][i] + bias;
      v = (o < HD) ? frelu(v) : 0.f;
      *(unsigned short*)(A2 + SWZ(r, r * 256 + o * 2)) = f2bf(v);
    }
  }
  for (int idx = tid; idx < 64 * 8; idx += 256) {
    int r = idx / 8, c = idx % 8;
    *(unsigned int*)(A2 + SWZ(r, r * 256 + 224 + c * 4)) = 0;
  }
  for (int c = tid; c < 448; c += 256)
    *(uint4*)(WBa + c * 16) = ((const uint4*)w2p)[c];
  __syncthreads();
  // -------- GEMM2 --------
  f32x4 acc2[7];
  #pragma unroll
  for (int nt = 0; nt < 7; ++nt) acc2[nt] = zero;
  #pragma unroll
  for (int ks = 0; ks < 4; ++ks) {
    char* rb = (ks & 1) ? WBb : WBa;
    char* wb = (ks & 1) ? WBa : WBb;
    uint4 st0, st1;
    if (ks < 3) {
      const uint4* wp = (const uint4*)w2p + (size_t)(ks + 1) * 448;
      st0 = wp[tid];
      if (tid < 192) st1 = wp[256 + tid];
    }
    bf16x8 a = *(const bf16x8*)(A2 + SWZ(arow, arow * 256 + (ks * 32 + lq * 8) * 2));
    #pragma unroll
    for (int nt = 0; nt < 7; ++nt) {
      bf16x8 b = *(const bf16x8*)(rb + (nt * 64 + lane) * 16);
      acc2[nt] = __builtin_amdgcn_mfma_f32_16x16x32_bf16(a, b, acc2[nt], 0, 0, 0);
    }
    if (ks < 3) {
      *(uint4*)(wb + tid * 16) = st0;
      if (tid < 192) *(uint4*)(wb + (256 + tid) * 16) = st1;
    }
    __syncthreads();
  }
  // epilogue2: e_new = e + 0.5*(C2+b2) -> bf16 into A2 exchange buffer (A2 dead now)
  #pragma unroll
  for (int nt = 0; nt < 7; ++nt) {
    int o = nt * 16 + l15;
    if (o < HD) {
      float bias = b2[o];
      #pragma unroll
      for (int i = 0; i < 4; ++i) {
        int r = w * 16 + lq * 4 + i;
        float ne = e[(size_t)(base + r) * HD + o] + 0.5f * (acc2[nt][i] + bias);
        *(unsigned short*)(A2 + SWZ(r, r * 256 + o * 2)) = f2bf(ne);
      }
    }
  }
  // zero exchange cols 100..111 (frag ks=9,lq=1 reads cols 96..103)
  if (tid < 192) {
    int row = tid / 3, j = tid % 3;
    *(uint2*)(A2 + SWZ(row, row * 256 + 200 + j * 8)) = (uint2){0u, 0u};
  }
  for (int c = tid; c < 256; c += 256)
    *(uint4*)(WBa + c * 16) = ((const uint4*)wf1p)[c];
  __syncthreads();
  // rebuild af[6..9] e-parts from exchange buffer (af[0..5] + af[6]@lq0 reused)
  if (lq >= 1) af[6] = *(const bf16x8*)(A2 + SWZ(arow, arow * 256 + (lq * 8 - 8) * 2));
  af[7] = *(const bf16x8*)(A2 + SWZ(arow, arow * 256 + (24 + lq * 8) * 2));
  af[8] = *(const bf16x8*)(A2 + SWZ(arow, arow * 256 + (56 + lq * 8) * 2));
  {
    bf16x8 zz; zz[0]=0; zz[1]=0; zz[2]=0; zz[3]=0; zz[4]=0; zz[5]=0; zz[6]=0; zz[7]=0;
    af[9] = (lq == 0) ? *(const bf16x8*)(A2 + SWZ(arow, arow * 256 + 88 * 2))
          : (lq == 1) ? *(const bf16x8*)(A2 + SWZ(arow, arow * 256 + 96 * 2))
                      : zz;
  }
  // -------- GEMM3 (final L1) --------
  f32x4 acc3[4];
  #pragma unroll
  for (int nt = 0; nt < 4; ++nt) acc3[nt] = zero;
  #pragma unroll
  for (int ks = 0; ks < 10; ++ks) {
    char* rb = (ks & 1) ? WBb : WBa;
    char* wb = (ks & 1) ? WBa : WBb;
    uint4 st0;
    if (ks < 9) st0 = ((const uint4*)wf1p)[(size_t)(ks + 1) * 256 + tid];
    #pragma unroll
    for (int nt = 0; nt < 4; ++nt) {
      bf16x8 b = *(const bf16x8*)(rb + (nt * 64 + lane) * 16);
      acc3[nt] = __builtin_amdgcn_mfma_f32_16x16x32_bf16(af[ks], b, acc3[nt], 0, 0, 0);
    }
    if (ks < 9) *(uint4*)(wb + tid * 16) = st0;
    __syncthreads();
  }
  // t = relu(C3+fb1) fp32 [64][52] stride 208 in A2 region
  #pragma unroll
  for (int nt = 0; nt < 4; ++nt) {
    int o = nt * 16 + l15;
    if (o < 50) {
      float bias = fb1[o];
      #pragma unroll
      for (int i = 0; i < 4; ++i) {
        int r = w * 16 + lq * 4 + i;
        *(float*)(A2 + r * 208 + o * 4) = frelu(acc3[nt][i] + bias);
      }
    }
  }
  __syncthreads();
  // fp32 tail: 4 threads per edge, 50->25->1
  int el = tid >> 2, q = tid & 3;
  const float* trow = (const float*)(A2 + el * 208);
  float s[7];
  {
    int i = 0;
    #pragma unroll
    for (int j0 = 0; j0 < 25; j0 += 4) { if (j0 + q < 25) s[i++] = b2s[j0 + q]; }
  }
  for (int k = 0; k < 50; ++k) {
    float tv = trow[k];
    int i = 0;
    #pragma unroll
    for (int j0 = 0; j0 < 25; j0 += 4) {
      if (j0 + q < 25) { s[i] = fmaf(tv, W2s[k * 25 + j0 + q], s[i]); ++i; }
    }
  }
  float racc = 0.f;
  {
    int i = 0;
    #pragma unroll
    for (int j0 = 0; j0 < 25; j0 += 4) {
      if (j0 + q < 25) { racc = fmaf(frelu(s[i]), W3s[j0 + q], racc); ++i; }
    }
  }
  racc += __shfl_xor(racc, 1, 4);
  racc += __shfl_xor(racc, 2, 4);
  if (q == 0) out[es[el]] = racc + b3s[0];
}

extern "C" void kernel_launch(void* const* d_in, const int* in_sizes, int n_in,
                              void* d_out, int out_size, void* d_ws, size_t ws_size,
                              hipStream_t stream) {
  (void)in_sizes; (void)n_in; (void)out_size; (void)ws_size;
  const float* x       = (const float*)d_in[0];
  const int*   eidx    = (const int*)  d_in[1];
  const float* eattr   = (const float*)d_in[2];
  const float* node_w  = (const float*)d_in[3];
  const float* node_b  = (const float*)d_in[4];
  const float* edge_w  = (const float*)d_in[5];
  const float* edge_b  = (const float*)d_in[6];
  const float* conv_w1 = (const float*)d_in[7];
  const float* conv_b1 = (const float*)d_in[8];
  const float* conv_w2 = (const float*)d_in[9];
  const float* conv_b2 = (const float*)d_in[10];
  const float* bn_g    = (const float*)d_in[11];
  const float* bn_b    = (const float*)d_in[12];
  const float* em_w1   = (const float*)d_in[13];
  const float* em_b1   = (const float*)d_in[14];
  const float* em_w2   = (const float*)d_in[15];
  const float* em_b2   = (const float*)d_in[16];
  const float* mlp_w1  = (const float*)d_in[17];
  const float* mlp_b1  = (const float*)d_in[18];
  const float* mlp_w2  = (const float*)d_in[19];
  const float* mlp_b2  = (const float*)d_in[20];
  const float* mlp_w3  = (const float*)d_in[21];
  const float* mlp_b3  = (const float*)d_in[22];

  const int* src = eidx;
  const int* dst = eidx + NE;

  // ws layout (max 202.15 MB; proven in rounds 5-6)
  char* ws = (char*)d_ws;
  float* h    = (float*)(ws);                     // 20,000,000
  float* agg  = (float*)(ws + 20000000);          // 20,000,000
  float* e    = (float*)(ws + 40000000);          // 160,000,000 (PERMUTED rows)
  unsigned short* w1p  = (unsigned short*)(ws + 200000000);  // 71,680
  unsigned short* w2p  = (unsigned short*)(ws + 200071680);  // 28,672
  unsigned short* wf1p = (unsigned short*)(ws + 200100352);  // 40,960
  int* rowptr = (int*)(ws + 200141312);           // 50,001 ints (+pad)
  int* cursor = (int*)(ws + 200341504);           // 50,000 ints
  int* eids   = (int*)(ws + 200541504);           // 400,000 ints
  int* part   = (int*)(ws + 202141504);           // 256 ints

  const int SCAN_NB = (NN + 256) / 256;
  // CSR build (dst-sorted permutation)
  hipMemsetAsync(cursor, 0, (size_t)NN * 4, stream);
  k_hist<<<(NE + 255) / 256, 256, 0, stream>>>(dst, cursor);
  k_scan_part<<<SCAN_NB, 256, 0, stream>>>(cursor, part);
  k_scan_top<<<1, 256, 0, stream>>>(part, SCAN_NB);
  k_scan_fill<<<SCAN_NB, 256, 0, stream>>>(cursor, part, rowptr);
  k_copy<<<SCAN_NB, 256, 0, stream>>>(rowptr, cursor);
  k_fill<<<(NE + 255) / 256, 256, 0, stream>>>(dst, cursor, eids);

  k_node_embed<<<(NN * HD + 255) / 256, 256, 0, stream>>>(x, node_w, node_b, h);
  {
    long long th = (long long)NE * 25;
    k_edge_embed_perm<<<(unsigned)((th + 255) / 256), 256, 0, stream>>>(eattr, eids, edge_w, edge_b, e);
  }

  k_pack<<<(10 * 4 * 64 + 255) / 256, 256, 0, stream>>>(mlp_w1, wf1p, 300, 50, 10, 4);

  for (int i = 0; i < 2; ++i) {
    k_gather<<<(NN + 63) / 64, 256, 0, stream>>>(h, e, rowptr, eids, src, agg);
    k_node_update<<<(NN + 63) / 64, 256, 0, stream>>>(
        h, agg, conv_w1 + i * HD * HD, conv_b1 + i * HD,
        conv_w2 + i * HD * HD, conv_b2 + i * HD, bn_g + i * HD, bn_b + i * HD);
    k_pack<<<(10 * 7 * 64 + 255) / 256, 256, 0, stream>>>(em_w1 + i * 30000, w1p, 300, 100, 10, 7);
    k_pack<<<(4 * 7 * 64 + 255) / 256, 256, 0, stream>>>(em_w2 + i * 10000,  w2p, 100, 100, 4, 7);
    if (i == 0) {
      k_edge_mfma<<<NE / 64, 256, 0, stream>>>(
          h, e, eids, src, dst, w1p, em_b1, w2p, em_b2);
    } else {
      k_edge_final_mfma<<<NE / 64, 256, 0, stream>>>(
          h, e, eids, src, dst, w1p, em_b1 + HD, w2p, em_b2 + HD,
          wf1p, mlp_b1, mlp_w2, mlp_b2, mlp_w3, mlp_b3, (float*)d_out);
    }
  }
}

// Round 8
// 1215.380 us; speedup vs baseline: 1.1809x; 1.1809x over previous
//
#include <hip/hip_runtime.h>

#define HD 100
#define NF 16
#define EF 8
#define NN 50000
#define NE 400000

typedef __attribute__((ext_vector_type(8))) short bf16x8;
typedef __attribute__((ext_vector_type(4))) float f32x4;

__device__ __forceinline__ float frelu(float v) { return v > 0.f ? v : 0.f; }
__device__ __forceinline__ unsigned short f2bf(float f) {
  unsigned int u = __float_as_uint(f);
  unsigned int r = (u + 0x7FFF + ((u >> 16) & 1)) >> 16;   // RNE
  return (unsigned short)r;
}
// XOR-swizzle: spread bank-aligned rows across 16B slots (G4 / T2)
__device__ __forceinline__ int SWZ(int row, int byte) { return byte ^ ((row & 7) << 4); }
__device__ __forceinline__ float4 L4(const float* p) { return *(const float4*)p; }
__device__ __forceinline__ bf16x8 cvt8(float4 a, float4 b) {
  bf16x8 r;
  r[0] = (short)f2bf(a.x); r[1] = (short)f2bf(a.y);
  r[2] = (short)f2bf(a.z); r[3] = (short)f2bf(a.w);
  r[4] = (short)f2bf(b.x); r[5] = (short)f2bf(b.y);
  r[6] = (short)f2bf(b.z); r[7] = (short)f2bf(b.w);
  return r;
}

// ---------------- weight pre-pack: W[K][N] fp32 -> frag-linear bf16 ----------------
__global__ __launch_bounds__(256) void k_pack(const float* __restrict__ W,
    unsigned short* __restrict__ out, int K, int N, int KS, int NT) {
  int t = blockIdx.x * 256 + threadIdx.x;
  if (t >= KS * NT * 64) return;
  int lane = t & 63, nt = (t >> 6) % NT, ks = (t >> 6) / NT;
  int kb = ks * 32 + (lane >> 4) * 8, n = nt * 16 + (lane & 15);
  unsigned short v[8];
  #pragma unroll
  for (int j = 0; j < 8; ++j) {
    int k = kb + j;
    float f = (k < K && n < N) ? W[(size_t)k * N + n] : 0.f;
    v[j] = f2bf(f);
  }
  uint4 o4;
  o4.x = (unsigned)v[0] | ((unsigned)v[1] << 16);
  o4.y = (unsigned)v[2] | ((unsigned)v[3] << 16);
  o4.z = (unsigned)v[4] | ((unsigned)v[5] << 16);
  o4.w = (unsigned)v[6] | ((unsigned)v[7] << 16);
  *(uint4*)&out[(size_t)t * 8] = o4;
}

__global__ __launch_bounds__(256) void k_node_embed(const float* __restrict__ x,
    const float* __restrict__ w, const float* __restrict__ b, float* __restrict__ h) {
  int t = blockIdx.x * 256 + threadIdx.x;
  int n = t / HD, o = t % HD;
  if (n >= NN) return;
  float acc = b[o];
  #pragma unroll
  for (int k = 0; k < NF; ++k) acc = fmaf(x[n * NF + k], w[k * HD + o], acc);
  h[(size_t)n * HD + o] = acc;
}

// e stored in PERMUTED (dst-sorted) layout; float4 outputs, LDS-staged weights
__global__ __launch_bounds__(256) void k_edge_embed_perm(const float* __restrict__ ea,
    const int* __restrict__ eids, const float* __restrict__ w, const float* __restrict__ b,
    float* __restrict__ e) {
  __shared__ float ws_[EF * HD];
  __shared__ float bs_[HD];
  int tid = threadIdx.x;
  for (int i = tid; i < EF * HD; i += 256) ws_[i] = w[i];
  for (int i = tid; i < HD; i += 256) bs_[i] = b[i];
  __syncthreads();
  long long t = (long long)blockIdx.x * 256 + tid;
  int p = (int)(t / 25), c4 = (int)(t % 25);
  if (p >= NE) return;
  int eid = eids[p];
  const float* ap = ea + (size_t)eid * EF;
  float4 a0 = L4(ap), a1 = L4(ap + 4);
  float av[8] = {a0.x, a0.y, a0.z, a0.w, a1.x, a1.y, a1.z, a1.w};
  int c0 = c4 * 4;
  float o0 = bs_[c0], o1 = bs_[c0 + 1], o2 = bs_[c0 + 2], o3 = bs_[c0 + 3];
  #pragma unroll
  for (int k = 0; k < EF; ++k) {
    const float* wr = &ws_[k * HD + c0];
    o0 = fmaf(av[k], wr[0], o0); o1 = fmaf(av[k], wr[1], o1);
    o2 = fmaf(av[k], wr[2], o2); o3 = fmaf(av[k], wr[3], o3);
  }
  float4 o; o.x = o0; o.y = o1; o.z = o2; o.w = o3;
  ((float4*)e)[(size_t)p * 25 + c4] = o;
}

// ---------------- CSR build ----------------
__global__ __launch_bounds__(256) void k_hist(const int* __restrict__ dst, int* __restrict__ deg) {
  int eid = blockIdx.x * 256 + threadIdx.x;
  if (eid < NE) atomicAdd(&deg[dst[eid]], 1);
}
__global__ __launch_bounds__(256) void k_scan_part(const int* __restrict__ deg, int* __restrict__ part) {
  __shared__ int sm[256];
  int i = blockIdx.x * 256 + threadIdx.x;
  sm[threadIdx.x] = (i < NN) ? deg[i] : 0;
  __syncthreads();
  for (int s = 128; s > 0; s >>= 1) {
    if (threadIdx.x < s) sm[threadIdx.x] += sm[threadIdx.x + s];
    __syncthreads();
  }
  if (threadIdx.x == 0) part[blockIdx.x] = sm[0];
}
__global__ __launch_bounds__(256) void k_scan_top(int* __restrict__ part, int nb) {
  __shared__ int sm[256];
  int v = (threadIdx.x < nb) ? part[threadIdx.x] : 0;
  sm[threadIdx.x] = v;
  __syncthreads();
  for (int off = 1; off < 256; off <<= 1) {
    int t = (threadIdx.x >= (unsigned)off) ? sm[threadIdx.x - off] : 0;
    __syncthreads();
    sm[threadIdx.x] += t;
    __syncthreads();
  }
  if (threadIdx.x < nb) part[threadIdx.x] = sm[threadIdx.x] - v;  // exclusive
}
__global__ __launch_bounds__(256) void k_scan_fill(const int* __restrict__ deg,
    const int* __restrict__ part, int* __restrict__ rowptr) {
  __shared__ int sm[256];
  int i = blockIdx.x * 256 + threadIdx.x;
  int v = (i < NN) ? deg[i] : 0;
  sm[threadIdx.x] = v;
  __syncthreads();
  for (int off = 1; off < 256; off <<= 1) {
    int t = (threadIdx.x >= (unsigned)off) ? sm[threadIdx.x - off] : 0;
    __syncthreads();
    sm[threadIdx.x] += t;
    __syncthreads();
  }
  if (i <= NN) rowptr[i] = part[blockIdx.x] + sm[threadIdx.x] - v;
}
__global__ __launch_bounds__(256) void k_copy(const int* __restrict__ a, int* __restrict__ b) {
  int i = blockIdx.x * 256 + threadIdx.x;
  if (i < NN) b[i] = a[i];
}
__global__ __launch_bounds__(256) void k_fill(const int* __restrict__ dst,
    int* __restrict__ cursor, int* __restrict__ eids) {
  int eid = blockIdx.x * 256 + threadIdx.x;
  if (eid >= NE) return;
  int pos = atomicAdd(&cursor[dst[eid]], 1);
  eids[pos] = eid;
}

// ---------------- gather-sum agg ----------------
__global__ __launch_bounds__(256) void k_gather(const float* __restrict__ h,
    const float* __restrict__ e, const int* __restrict__ rowptr,
    const int* __restrict__ eids, const int* __restrict__ src, float* __restrict__ agg) {
  int slot = threadIdx.x >> 2, sub = threadIdx.x & 3;
  int n = blockIdx.x * 64 + slot;
  if (n >= NN) return;
  int r0 = rowptr[n], r1 = rowptr[n + 1];
  float4 acc[7];
  #pragma unroll
  for (int i = 0; i < 7; ++i) { acc[i].x = 0.f; acc[i].y = 0.f; acc[i].z = 0.f; acc[i].w = 0.f; }
  for (int p = r0; p < r1; ++p) {
    int s = src[eids[p]];
    const float4* hp = (const float4*)&h[(size_t)s * HD];
    const float4* ep = (const float4*)&e[(size_t)p * HD];
    #pragma unroll
    for (int i = 0; i < 7; ++i) {
      int c = sub + i * 4;
      if (c < 25) {
        float4 hv = hp[c], ev = ep[c];
        acc[i].x += frelu(hv.x + ev.x);
        acc[i].y += frelu(hv.y + ev.y);
        acc[i].z += frelu(hv.z + ev.z);
        acc[i].w += frelu(hv.w + ev.w);
      }
    }
  }
  float4* ap = (float4*)&agg[(size_t)n * HD];
  #pragma unroll
  for (int i = 0; i < 7; ++i) {
    int c = sub + i * 4;
    if (c < 25) ap[c] = acc[i];
  }
}

// fp32 node update (accuracy-critical path)
__global__ __launch_bounds__(256) void k_node_update(float* __restrict__ h,
    const float* __restrict__ agg,
    const float* __restrict__ w1, const float* __restrict__ b1,
    const float* __restrict__ w2, const float* __restrict__ b2,
    const float* __restrict__ gamma, const float* __restrict__ beta) {
  __shared__ float zs[64 * 101];
  int tid = threadIdx.x;
  int base = blockIdx.x * 64;
  for (int idx = tid; idx < 64 * HD; idx += 256) {
    int n = idx / HD, k = idx % HD;
    int gn = base + n; int cn = gn < NN ? gn : NN - 1;
    zs[n * 101 + k] = h[(size_t)cn * HD + k] + agg[(size_t)cn * HD + k];
  }
  __syncthreads();
  int el = tid & 63;
  int o0 = __builtin_amdgcn_readfirstlane((tid >> 6) * 25);
  float* row = &zs[el * 101];
  float acc[25];
  #pragma unroll
  for (int j = 0; j < 25; ++j) acc[j] = b1[o0 + j];
  for (int k = 0; k < HD; ++k) {
    float a = row[k];
    const float* wr = &w1[k * HD + o0];
    #pragma unroll
    for (int j = 0; j < 25; ++j) acc[j] = fmaf(a, wr[j], acc[j]);
  }
  __syncthreads();
  #pragma unroll
  for (int j = 0; j < 25; ++j) row[o0 + j] = frelu(acc[j]);
  __syncthreads();
  float acc2[25];
  #pragma unroll
  for (int j = 0; j < 25; ++j) acc2[j] = b2[o0 + j];
  for (int k = 0; k < HD; ++k) {
    float a = row[k];
    const float* wr = &w2[k * HD + o0];
    #pragma unroll
    for (int j = 0; j < 25; ++j) acc2[j] = fmaf(a, wr[j], acc2[j]);
  }
  int gn = base + el;
  if (gn < NN) {
    const float bninv = 0.99999500003749973f;  // 1/sqrt(1+1e-5)
    #pragma unroll
    for (int j = 0; j < 25; ++j) {
      int o = o0 + j;
      float bn = acc2[j] * (gamma[o] * bninv) + beta[o];
      h[(size_t)gn * HD + o] = (h[(size_t)gn * HD + o] + frelu(bn)) * 0.5f;
    }
  }
}

// ---------------- layer-1 MFMA edge update: register-A, e RMW from regs ----------------
// launch_bounds (256,2): VGPR cap 256 — round 7's (256,3) forced spills (1.5 GB scratch WRITE)
__global__ __launch_bounds__(256, 2) void k_edge_mfma(
    const float* __restrict__ h, float* __restrict__ e,
    const int* __restrict__ eids, const int* __restrict__ src, const int* __restrict__ dst,
    const unsigned short* __restrict__ w1p, const float* __restrict__ b1,
    const unsigned short* __restrict__ w2p, const float* __restrict__ b2) {
  __shared__ __align__(16) char lds[31232];
  char* A2  = lds;                 // 16384: GEMM2 A (bf16 [64][128] swizzled)
  char* WBa = lds + 16384;         // 7168
  char* WBb = lds + 23552;         // 7168
  int* ss  = (int*)(lds + 30720);
  int* ds_ = (int*)(lds + 30976);
  int tid = threadIdx.x;
  int base = blockIdx.x * 64;
  if (tid < 64) { int eid = eids[base + tid]; ss[tid] = src[eid]; ds_[tid] = dst[eid]; }
  for (int c = tid; c < 448; c += 256)
    *(uint4*)(WBa + c * 16) = ((const uint4*)w1p)[c];
  __syncthreads();

  int lane = tid & 63, w = tid >> 6;
  int l15 = lane & 15, lq = lane >> 4;
  int arow = w * 16 + l15;
  const float* hs = h + (size_t)ss[arow] * HD;
  const float* hd = h + (size_t)ds_[arow] * HD;
  const float* ep = e + (size_t)(base + arow) * HD;
  float4 z4; z4.x = z4.y = z4.z = z4.w = 0.f;

  // A fragments in registers: af[ks] = bf16 of row elems k=ks*32+lq*8 .. +7
  bf16x8 af[10];
  af[0] = cvt8(L4(hs + lq * 8),      L4(hs + lq * 8 + 4));
  af[1] = cvt8(L4(hs + 32 + lq * 8), L4(hs + 36 + lq * 8));
  af[2] = cvt8(L4(hs + 64 + lq * 8), L4(hs + 68 + lq * 8));
  af[3] = (lq == 0) ? cvt8(L4(hs + 96), L4(hd))
                    : cvt8(L4(hd + lq * 8 - 4), L4(hd + lq * 8));
  af[4] = cvt8(L4(hd + 28 + lq * 8), L4(hd + 32 + lq * 8));
  af[5] = cvt8(L4(hd + 60 + lq * 8), L4(hd + 64 + lq * 8));
  af[6] = (lq == 0) ? cvt8(L4(hd + 92), L4(hd + 96))
                    : cvt8(L4(ep + lq * 8 - 8), L4(ep + lq * 8 - 4));
  af[7] = cvt8(L4(ep + 24 + lq * 8), L4(ep + 28 + lq * 8));
  af[8] = cvt8(L4(ep + 56 + lq * 8), L4(ep + 60 + lq * 8));
  af[9] = (lq == 0) ? cvt8(L4(ep + 88), L4(ep + 92))
        : (lq == 1) ? cvt8(L4(ep + 96), z4)
                    : cvt8(z4, z4);

  f32x4 zero = {0.f, 0.f, 0.f, 0.f};
  f32x4 acc[7];
  #pragma unroll
  for (int nt = 0; nt < 7; ++nt) acc[nt] = zero;
  #pragma unroll
  for (int ks = 0; ks < 10; ++ks) {
    char* rb = (ks & 1) ? WBb : WBa;
    char* wb = (ks & 1) ? WBa : WBb;
    uint4 st0, st1;
    if (ks < 9) {
      const uint4* wp = (const uint4*)w1p + (size_t)(ks + 1) * 448;
      st0 = wp[tid];
      if (tid < 192) st1 = wp[256 + tid];
    }
    #pragma unroll
    for (int nt = 0; nt < 7; ++nt) {
      bf16x8 b = *(const bf16x8*)(rb + (nt * 64 + lane) * 16);
      acc[nt] = __builtin_amdgcn_mfma_f32_16x16x32_bf16(af[ks], b, acc[nt], 0, 0, 0);
    }
    if (ks < 9) {
      *(uint4*)(wb + tid * 16) = st0;
      if (tid < 192) *(uint4*)(wb + (256 + tid) * 16) = st1;
    }
    __syncthreads();
  }

  // epilogue1: relu(C1+b1) -> bf16 A2 [64][128] stride 256 (swizzled)
  #pragma unroll
  for (int nt = 0; nt < 7; ++nt) {
    int o = nt * 16 + l15;
    float bias = (o < HD) ? b1[o] : 0.f;
    #pragma unroll
    for (int i = 0; i < 4; ++i) {
      int r = w * 16 + lq * 4 + i;
      float v = acc[nt][i] + bias;
      v = (o < HD) ? frelu(v) : 0.f;
      *(unsigned short*)(A2 + SWZ(r, r * 256 + o * 2)) = f2bf(v);
    }
  }
  for (int idx = tid; idx < 64 * 8; idx += 256) {
    int r = idx / 8, c = idx % 8;
    *(unsigned int*)(A2 + SWZ(r, r * 256 + 224 + c * 4)) = 0;
  }
  for (int c = tid; c < 448; c += 256)
    *(uint4*)(WBa + c * 16) = ((const uint4*)w2p)[c];
  __syncthreads();

  f32x4 acc2[7];
  #pragma unroll
  for (int nt = 0; nt < 7; ++nt) acc2[nt] = zero;
  #pragma unroll
  for (int ks = 0; ks < 4; ++ks) {
    char* rb = (ks & 1) ? WBb : WBa;
    char* wb = (ks & 1) ? WBa : WBb;
    uint4 st0, st1;
    if (ks < 3) {
      const uint4* wp = (const uint4*)w2p + (size_t)(ks + 1) * 448;
      st0 = wp[tid];
      if (tid < 192) st1 = wp[256 + tid];
    }
    bf16x8 a = *(const bf16x8*)(A2 + SWZ(arow, arow * 256 + (ks * 32 + lq * 8) * 2));
    #pragma unroll
    for (int nt = 0; nt < 7; ++nt) {
      bf16x8 b = *(const bf16x8*)(rb + (nt * 64 + lane) * 16);
      acc2[nt] = __builtin_amdgcn_mfma_f32_16x16x32_bf16(a, b, acc2[nt], 0, 0, 0);
    }
    if (ks < 3) {
      *(uint4*)(wb + tid * 16) = st0;
      if (tid < 192) *(uint4*)(wb + (256 + tid) * 16) = st1;
    }
    __syncthreads();
  }
  // epilogue2: e += 0.5*(C2+b2) directly from C-layout regs (64B-coalesced per 16 lanes)
  #pragma unroll
  for (int nt = 0; nt < 7; ++nt) {
    int o = nt * 16 + l15;
    if (o < HD) {
      float bias = b2[o];
      #pragma unroll
      for (int i = 0; i < 4; ++i) {
        int r = w * 16 + lq * 4 + i;
        size_t p = (size_t)(base + r) * HD + o;
        e[p] = e[p] + 0.5f * (acc2[nt][i] + bias);
      }
    }
  }
}

// ------- layer-2 edge update FUSED with final MLP: register-A throughout -------
__global__ __launch_bounds__(256, 2) void k_edge_final_mfma(
    const float* __restrict__ h, const float* __restrict__ e,
    const int* __restrict__ eids, const int* __restrict__ src, const int* __restrict__ dst,
    const unsigned short* __restrict__ w1p, const float* __restrict__ b1,
    const unsigned short* __restrict__ w2p, const float* __restrict__ b2,
    const unsigned short* __restrict__ wf1p, const float* __restrict__ fb1,
    const float* __restrict__ fw2, const float* __restrict__ fb2,
    const float* __restrict__ fw3, const float* __restrict__ fb3,
    float* __restrict__ out) {
  __shared__ __align__(16) char lds[36704];
  char* A2  = lds;                      // 16384: GEMM2-A / e_new exchange / t fp32
  char* WBa = lds + 16384;              // 7168
  char* WBb = lds + 23552;              // 7168
  float* W2s = (float*)(lds + 30720);   // 1250
  float* b2s = (float*)(lds + 35720);   // 25
  float* W3s = (float*)(lds + 35820);   // 25
  float* b3s = (float*)(lds + 35920);   // 1
  int* es  = (int*)(lds + 35924);       // 64
  int* ss  = (int*)(lds + 36180);       // 64
  int* ds_ = (int*)(lds + 36436);       // 64
  int tid = threadIdx.x;
  int base = blockIdx.x * 64;
  if (tid < 64) { int eid = eids[base + tid]; es[tid] = eid; ss[tid] = src[eid]; ds_[tid] = dst[eid]; }
  for (int c = tid; c < 1250; c += 256) W2s[c] = fw2[c];
  if (tid < 25) { b2s[tid] = fb2[tid]; W3s[tid] = fw3[tid]; }
  if (tid == 0) b3s[0] = fb3[0];
  for (int c = tid; c < 448; c += 256)
    *(uint4*)(WBa + c * 16) = ((const uint4*)w1p)[c];
  __syncthreads();

  int lane = tid & 63, w = tid >> 6;
  int l15 = lane & 15, lq = lane >> 4;
  int arow = w * 16 + l15;
  const float* hs = h + (size_t)ss[arow] * HD;
  const float* hd = h + (size_t)ds_[arow] * HD;
  const float* ep = e + (size_t)(base + arow) * HD;
  float4 z4; z4.x = z4.y = z4.z = z4.w = 0.f;

  bf16x8 af[10];
  af[0] = cvt8(L4(hs + lq * 8),      L4(hs + lq * 8 + 4));
  af[1] = cvt8(L4(hs + 32 + lq * 8), L4(hs + 36 + lq * 8));
  af[2] = cvt8(L4(hs + 64 + lq * 8), L4(hs + 68 + lq * 8));
  af[3] = (lq == 0) ? cvt8(L4(hs + 96), L4(hd))
                    : cvt8(L4(hd + lq * 8 - 4), L4(hd + lq * 8));
  af[4] = cvt8(L4(hd + 28 + lq * 8), L4(hd + 32 + lq * 8));
  af[5] = cvt8(L4(hd + 60 + lq * 8), L4(hd + 64 + lq * 8));
  af[6] = (lq == 0) ? cvt8(L4(hd + 92), L4(hd + 96))
                    : cvt8(L4(ep + lq * 8 - 8), L4(ep + lq * 8 - 4));
  af[7] = cvt8(L4(ep + 24 + lq * 8), L4(ep + 28 + lq * 8));
  af[8] = cvt8(L4(ep + 56 + lq * 8), L4(ep + 60 + lq * 8));
  af[9] = (lq == 0) ? cvt8(L4(ep + 88), L4(ep + 92))
        : (lq == 1) ? cvt8(L4(ep + 96), z4)
                    : cvt8(z4, z4);

  f32x4 zero = {0.f, 0.f, 0.f, 0.f};
  // -------- GEMM1 --------
  f32x4 acc[7];
  #pragma unroll
  for (int nt = 0; nt < 7; ++nt) acc[nt] = zero;
  #pragma unroll
  for (int ks = 0; ks < 10; ++ks) {
    char* rb = (ks & 1) ? WBb : WBa;
    char* wb = (ks & 1) ? WBa : WBb;
    uint4 st0, st1;
    if (ks < 9) {
      const uint4* wp = (const uint4*)w1p + (size_t)(ks + 1) * 448;
      st0 = wp[tid];
      if (tid < 192) st1 = wp[256 + tid];
    }
    #pragma unroll
    for (int nt = 0; nt < 7; ++nt) {
      bf16x8 b = *(const bf16x8*)(rb + (nt * 64 + lane) * 16);
      acc[nt] = __builtin_amdgcn_mfma_f32_16x16x32_bf16(af[ks], b, acc[nt], 0, 0, 0);
    }
    if (ks < 9) {
      *(uint4*)(wb + tid * 16) = st0;
      if (tid < 192) *(uint4*)(wb + (256 + tid) * 16) = st1;
    }
    __syncthreads();
  }
  // epilogue1: relu(C1+b1) -> bf16 A2
  #pragma unroll
  for (int nt = 0; nt < 7; ++nt) {
    int o = nt * 16 + l15;
    float bias = (o < HD) ? b1[o] : 0.f;
    #pragma unroll
    for (int i = 0; i < 4; ++i) {
      int r = w * 16 + lq * 4 + i;
      float v = acc[nt][i] + bias;
      v = (o < HD) ? frelu(v) : 0.f;
      *(unsigned short*)(A2 + SWZ(r, r * 256 + o * 2)) = f2bf(v);
    }
  }
  for (int idx = tid; idx < 64 * 8; idx += 256) {
    int r = idx / 8, c = idx % 8;
    *(unsigned int*)(A2 + SWZ(r, r * 256 + 224 + c * 4)) = 0;
  }
  for (int c = tid; c < 448; c += 256)
    *(uint4*)(WBa + c * 16) = ((const uint4*)w2p)[c];
  __syncthreads();
  // -------- GEMM2 --------
  f32x4 acc2[7];
  #pragma unroll
  for (int nt = 0; nt < 7; ++nt) acc2[nt] = zero;
  #pragma unroll
  for (int ks = 0; ks < 4; ++ks) {
    char* rb = (ks & 1) ? WBb : WBa;
    char* wb = (ks & 1) ? WBa : WBb;
    uint4 st0, st1;
    if (ks < 3) {
      const uint4* wp = (const uint4*)w2p + (size_t)(ks + 1) * 448;
      st0 = wp[tid];
      if (tid < 192) st1 = wp[256 + tid];
    }
    bf16x8 a = *(const bf16x8*)(A2 + SWZ(arow, arow * 256 + (ks * 32 + lq * 8) * 2));
    #pragma unroll
    for (int nt = 0; nt < 7; ++nt) {
      bf16x8 b = *(const bf16x8*)(rb + (nt * 64 + lane) * 16);
      acc2[nt] = __builtin_amdgcn_mfma_f32_16x16x32_bf16(a, b, acc2[nt], 0, 0, 0);
    }
    if (ks < 3) {
      *(uint4*)(wb + tid * 16) = st0;
      if (tid < 192) *(uint4*)(wb + (256 + tid) * 16) = st1;
    }
    __syncthreads();
  }
  // epilogue2: e_new = e + 0.5*(C2+b2) -> bf16 into A2 exchange buffer (A2 dead now)
  #pragma unroll
  for (int nt = 0; nt < 7; ++nt) {
    int o = nt * 16 + l15;
    if (o < HD) {
      float bias = b2[o];
      #pragma unroll
      for (int i = 0; i < 4; ++i) {
        int r = w * 16 + lq * 4 + i;
        float ne = e[(size_t)(base + r) * HD + o] + 0.5f * (acc2[nt][i] + bias);
        *(unsigned short*)(A2 + SWZ(r, r * 256 + o * 2)) = f2bf(ne);
      }
    }
  }
  // zero exchange cols 100..111 (frag ks=9,lq=1 reads cols 96..103)
  if (tid < 192) {
    int row = tid / 3, j = tid % 3;
    *(uint2*)(A2 + SWZ(row, row * 256 + 200 + j * 8)) = (uint2){0u, 0u};
  }
  for (int c = tid; c < 256; c += 256)
    *(uint4*)(WBa + c * 16) = ((const uint4*)wf1p)[c];
  __syncthreads();
  // rebuild af[6..9] e-parts from exchange buffer (af[0..5] + af[6]@lq0 reused)
  if (lq >= 1) af[6] = *(const bf16x8*)(A2 + SWZ(arow, arow * 256 + (lq * 8 - 8) * 2));
  af[7] = *(const bf16x8*)(A2 + SWZ(arow, arow * 256 + (24 + lq * 8) * 2));
  af[8] = *(const bf16x8*)(A2 + SWZ(arow, arow * 256 + (56 + lq * 8) * 2));
  {
    bf16x8 zz; zz[0]=0; zz[1]=0; zz[2]=0; zz[3]=0; zz[4]=0; zz[5]=0; zz[6]=0; zz[7]=0;
    af[9] = (lq == 0) ? *(const bf16x8*)(A2 + SWZ(arow, arow * 256 + 88 * 2))
          : (lq == 1) ? *(const bf16x8*)(A2 + SWZ(arow, arow * 256 + 96 * 2))
                      : zz;
  }
  // -------- GEMM3 (final L1) --------
  f32x4 acc3[4];
  #pragma unroll
  for (int nt = 0; nt < 4; ++nt) acc3[nt] = zero;
  #pragma unroll
  for (int ks = 0; ks < 10; ++ks) {
    char* rb = (ks & 1) ? WBb : WBa;
    char* wb = (ks & 1) ? WBa : WBb;
    uint4 st0;
    if (ks < 9) st0 = ((const uint4*)wf1p)[(size_t)(ks + 1) * 256 + tid];
    #pragma unroll
    for (int nt = 0; nt < 4; ++nt) {
      bf16x8 b = *(const bf16x8*)(rb + (nt * 64 + lane) * 16);
      acc3[nt] = __builtin_amdgcn_mfma_f32_16x16x32_bf16(af[ks], b, acc3[nt], 0, 0, 0);
    }
    if (ks < 9) *(uint4*)(wb + tid * 16) = st0;
    __syncthreads();
  }
  // t = relu(C3+fb1) fp32 [64][52] stride 208 in A2 region
  #pragma unroll
  for (int nt = 0; nt < 4; ++nt) {
    int o = nt * 16 + l15;
    if (o < 50) {
      float bias = fb1[o];
      #pragma unroll
      for (int i = 0; i < 4; ++i) {
        int r = w * 16 + lq * 4 + i;
        *(float*)(A2 + r * 208 + o * 4) = frelu(acc3[nt][i] + bias);
      }
    }
  }
  __syncthreads();
  // fp32 tail: 4 threads per edge, 50->25->1
  int el = tid >> 2, q = tid & 3;
  const float* trow = (const float*)(A2 + el * 208);
  float s[7];
  {
    int i = 0;
    #pragma unroll
    for (int j0 = 0; j0 < 25; j0 += 4) { if (j0 + q < 25) s[i++] = b2s[j0 + q]; }
  }
  for (int k = 0; k < 50; ++k) {
    float tv = trow[k];
    int i = 0;
    #pragma unroll
    for (int j0 = 0; j0 < 25; j0 += 4) {
      if (j0 + q < 25) { s[i] = fmaf(tv, W2s[k * 25 + j0 + q], s[i]); ++i; }
    }
  }
  float racc = 0.f;
  {
    int i = 0;
    #pragma unroll
    for (int j0 = 0; j0 < 25; j0 += 4) {
      if (j0 + q < 25) { racc = fmaf(frelu(s[i]), W3s[j0 + q], racc); ++i; }
    }
  }
  racc += __shfl_xor(racc, 1, 4);
  racc += __shfl_xor(racc, 2, 4);
  if (q == 0) out[es[el]] = racc + b3s[0];
}

extern "C" void kernel_launch(void* const* d_in, const int* in_sizes, int n_in,
                              void* d_out, int out_size, void* d_ws, size_t ws_size,
                              hipStream_t stream) {
  (void)in_sizes; (void)n_in; (void)out_size; (void)ws_size;
  const float* x       = (const float*)d_in[0];
  const int*   eidx    = (const int*)  d_in[1];
  const float* eattr   = (const float*)d_in[2];
  const float* node_w  = (const float*)d_in[3];
  const float* node_b  = (const float*)d_in[4];
  const float* edge_w  = (const float*)d_in[5];
  const float* edge_b  = (const float*)d_in[6];
  const float* conv_w1 = (const float*)d_in[7];
  const float* conv_b1 = (const float*)d_in[8];
  const float* conv_w2 = (const float*)d_in[9];
  const float* conv_b2 = (const float*)d_in[10];
  const float* bn_g    = (const float*)d_in[11];
  const float* bn_b    = (const float*)d_in[12];
  const float* em_w1   = (const float*)d_in[13];
  const float* em_b1   = (const float*)d_in[14];
  const float* em_w2   = (const float*)d_in[15];
  const float* em_b2   = (const float*)d_in[16];
  const float* mlp_w1  = (const float*)d_in[17];
  const float* mlp_b1  = (const float*)d_in[18];
  const float* mlp_w2  = (const float*)d_in[19];
  const float* mlp_b2  = (const float*)d_in[20];
  const float* mlp_w3  = (const float*)d_in[21];
  const float* mlp_b3  = (const float*)d_in[22];

  const int* src = eidx;
  const int* dst = eidx + NE;

  // ws layout (max 202.15 MB; proven in rounds 5-6)
  char* ws = (char*)d_ws;
  float* h    = (float*)(ws);                     // 20,000,000
  float* agg  = (float*)(ws + 20000000);          // 20,000,000
  float* e    = (float*)(ws + 40000000);          // 160,000,000 (PERMUTED rows)
  unsigned short* w1p  = (unsigned short*)(ws + 200000000);  // 71,680
  unsigned short* w2p  = (unsigned short*)(ws + 200071680);  // 28,672
  unsigned short* wf1p = (unsigned short*)(ws + 200100352);  // 40,960
  int* rowptr = (int*)(ws + 200141312);           // 50,001 ints (+pad)
  int* cursor = (int*)(ws + 200341504);           // 50,000 ints
  int* eids   = (int*)(ws + 200541504);           // 400,000 ints
  int* part   = (int*)(ws + 202141504);           // 256 ints

  const int SCAN_NB = (NN + 256) / 256;
  // CSR build (dst-sorted permutation)
  hipMemsetAsync(cursor, 0, (size_t)NN * 4, stream);
  k_hist<<<(NE + 255) / 256, 256, 0, stream>>>(dst, cursor);
  k_scan_part<<<SCAN_NB, 256, 0, stream>>>(cursor, part);
  k_scan_top<<<1, 256, 0, stream>>>(part, SCAN_NB);
  k_scan_fill<<<SCAN_NB, 256, 0, stream>>>(cursor, part, rowptr);
  k_copy<<<SCAN_NB, 256, 0, stream>>>(rowptr, cursor);
  k_fill<<<(NE + 255) / 256, 256, 0, stream>>>(dst, cursor, eids);

  k_node_embed<<<(NN * HD + 255) / 256, 256, 0, stream>>>(x, node_w, node_b, h);
  {
    long long th = (long long)NE * 25;
    k_edge_embed_perm<<<(unsigned)((th + 255) / 256), 256, 0, stream>>>(eattr, eids, edge_w, edge_b, e);
  }

  k_pack<<<(10 * 4 * 64 + 255) / 256, 256, 0, stream>>>(mlp_w1, wf1p, 300, 50, 10, 4);

  for (int i = 0; i < 2; ++i) {
    k_gather<<<(NN + 63) / 64, 256, 0, stream>>>(h, e, rowptr, eids, src, agg);
    k_node_update<<<(NN + 63) / 64, 256, 0, stream>>>(
        h, agg, conv_w1 + i * HD * HD, conv_b1 + i * HD,
        conv_w2 + i * HD * HD, conv_b2 + i * HD, bn_g + i * HD, bn_b + i * HD);
    k_pack<<<(10 * 7 * 64 + 255) / 256, 256, 0, stream>>>(em_w1 + i * 30000, w1p, 300, 100, 10, 7);
    k_pack<<<(4 * 7 * 64 + 255) / 256, 256, 0, stream>>>(em_w2 + i * 10000,  w2p, 100, 100, 4, 7);
    if (i == 0) {
      k_edge_mfma<<<NE / 64, 256, 0, stream>>>(
          h, e, eids, src, dst, w1p, em_b1, w2p, em_b2);
    } else {
      k_edge_final_mfma<<<NE / 64, 256, 0, stream>>>(
          h, e, eids, src, dst, w1p, em_b1 + HD, w2p, em_b2 + HD,
          wf1p, mlp_b1, mlp_w2, mlp_b2, mlp_w3, mlp_b3, (float*)d_out);
    }
  }
}

// Round 9
// 955.942 us; speedup vs baseline: 1.5014x; 1.2714x over previous
//
#include <hip/hip_runtime.h>

#define HD 100
#define NF 16
#define EF 8
#define NN 50000
#define NE 400000
#define NT64 6250   // NE/64 tiles

typedef __attribute__((ext_vector_type(8))) short bf16x8;
typedef __attribute__((ext_vector_type(4))) float f32x4;

__device__ __forceinline__ float frelu(float v) { return v > 0.f ? v : 0.f; }
__device__ __forceinline__ unsigned short f2bf(float f) {
  unsigned int u = __float_as_uint(f);
  unsigned int r = (u + 0x7FFF + ((u >> 16) & 1)) >> 16;   // RNE
  return (unsigned short)r;
}
// XOR-swizzle: spread bank-aligned rows across 16B slots (G4 / T2)
__device__ __forceinline__ int SWZ(int row, int byte) { return byte ^ ((row & 7) << 4); }
__device__ __forceinline__ float4 L4(const float* p) { return *(const float4*)p; }
__device__ __forceinline__ bf16x8 cvt8(float4 a, float4 b) {
  bf16x8 r;
  r[0] = (short)f2bf(a.x); r[1] = (short)f2bf(a.y);
  r[2] = (short)f2bf(a.z); r[3] = (short)f2bf(a.w);
  r[4] = (short)f2bf(b.x); r[5] = (short)f2bf(b.y);
  r[6] = (short)f2bf(b.z); r[7] = (short)f2bf(b.w);
  return r;
}

// A-fragment for 320-wide row [h_src|h_dst|e|pad]: ks is compile-time (unrolled callers)
__device__ __forceinline__ bf16x8 frag_a(int ks, int lq,
    const float* hs, const float* hd, const float* ep) {
  float4 z4; z4.x = z4.y = z4.z = z4.w = 0.f;
  if (ks <= 2) return cvt8(L4(hs + ks * 32 + lq * 8), L4(hs + ks * 32 + lq * 8 + 4));
  if (ks == 3) return (lq == 0) ? cvt8(L4(hs + 96), L4(hd))
                                : cvt8(L4(hd + lq * 8 - 4), L4(hd + lq * 8));
  if (ks <= 5) return cvt8(L4(hd + (ks - 3) * 32 - 4 + lq * 8),
                           L4(hd + (ks - 3) * 32 + lq * 8));
  if (ks == 6) return (lq == 0) ? cvt8(L4(hd + 92), L4(hd + 96))
                                : cvt8(L4(ep + lq * 8 - 8), L4(ep + lq * 8 - 4));
  if (ks <= 8) return cvt8(L4(ep + (ks - 7) * 32 + 24 + lq * 8),
                           L4(ep + (ks - 7) * 32 + 28 + lq * 8));
  return (lq == 0) ? cvt8(L4(ep + 88), L4(ep + 92))
       : (lq == 1) ? cvt8(L4(ep + 96), z4) : cvt8(z4, z4);
}

// ---------------- weight pre-pack: W[K][N] fp32 -> frag-linear bf16 ----------------
__global__ __launch_bounds__(256) void k_pack(const float* __restrict__ W,
    unsigned short* __restrict__ out, int K, int N, int KS, int NT) {
  int t = blockIdx.x * 256 + threadIdx.x;
  if (t >= KS * NT * 64) return;
  int lane = t & 63, nt = (t >> 6) % NT, ks = (t >> 6) / NT;
  int kb = ks * 32 + (lane >> 4) * 8, n = nt * 16 + (lane & 15);
  unsigned short v[8];
  #pragma unroll
  for (int j = 0; j < 8; ++j) {
    int k = kb + j;
    float f = (k < K && n < N) ? W[(size_t)k * N + n] : 0.f;
    v[j] = f2bf(f);
  }
  uint4 o4;
  o4.x = (unsigned)v[0] | ((unsigned)v[1] << 16);
  o4.y = (unsigned)v[2] | ((unsigned)v[3] << 16);
  o4.z = (unsigned)v[4] | ((unsigned)v[5] << 16);
  o4.w = (unsigned)v[6] | ((unsigned)v[7] << 16);
  *(uint4*)&out[(size_t)t * 8] = o4;
}

__global__ __launch_bounds__(256) void k_node_embed(const float* __restrict__ x,
    const float* __restrict__ w, const float* __restrict__ b, float* __restrict__ h) {
  int t = blockIdx.x * 256 + threadIdx.x;
  int n = t / HD, o = t % HD;
  if (n >= NN) return;
  float acc = b[o];
  #pragma unroll
  for (int k = 0; k < NF; ++k) acc = fmaf(x[n * NF + k], w[k * HD + o], acc);
  h[(size_t)n * HD + o] = acc;
}

// e stored in PERMUTED (dst-sorted) layout
__global__ __launch_bounds__(256) void k_edge_embed_perm(const float* __restrict__ ea,
    const int* __restrict__ eids, const float* __restrict__ w, const float* __restrict__ b,
    float* __restrict__ e) {
  __shared__ float ws_[EF * HD];
  __shared__ float bs_[HD];
  int tid = threadIdx.x;
  for (int i = tid; i < EF * HD; i += 256) ws_[i] = w[i];
  for (int i = tid; i < HD; i += 256) bs_[i] = b[i];
  __syncthreads();
  long long t = (long long)blockIdx.x * 256 + tid;
  int p = (int)(t / 25), c4 = (int)(t % 25);
  if (p >= NE) return;
  int eid = eids[p];
  const float* ap = ea + (size_t)eid * EF;
  float4 a0 = L4(ap), a1 = L4(ap + 4);
  float av[8] = {a0.x, a0.y, a0.z, a0.w, a1.x, a1.y, a1.z, a1.w};
  int c0 = c4 * 4;
  float o0 = bs_[c0], o1 = bs_[c0 + 1], o2 = bs_[c0 + 2], o3 = bs_[c0 + 3];
  #pragma unroll
  for (int k = 0; k < EF; ++k) {
    const float* wr = &ws_[k * HD + c0];
    o0 = fmaf(av[k], wr[0], o0); o1 = fmaf(av[k], wr[1], o1);
    o2 = fmaf(av[k], wr[2], o2); o3 = fmaf(av[k], wr[3], o3);
  }
  float4 o; o.x = o0; o.y = o1; o.z = o2; o.w = o3;
  ((float4*)e)[(size_t)p * 25 + c4] = o;
}

// ---------------- CSR build ----------------
__global__ __launch_bounds__(256) void k_hist(const int* __restrict__ dst, int* __restrict__ deg) {
  int eid = blockIdx.x * 256 + threadIdx.x;
  if (eid < NE) atomicAdd(&deg[dst[eid]], 1);
}
__global__ __launch_bounds__(256) void k_scan_part(const int* __restrict__ deg, int* __restrict__ part) {
  __shared__ int sm[256];
  int i = blockIdx.x * 256 + threadIdx.x;
  sm[threadIdx.x] = (i < NN) ? deg[i] : 0;
  __syncthreads();
  for (int s = 128; s > 0; s >>= 1) {
    if (threadIdx.x < s) sm[threadIdx.x] += sm[threadIdx.x + s];
    __syncthreads();
  }
  if (threadIdx.x == 0) part[blockIdx.x] = sm[0];
}
__global__ __launch_bounds__(256) void k_scan_top(int* __restrict__ part, int nb) {
  __shared__ int sm[256];
  int v = (threadIdx.x < nb) ? part[threadIdx.x] : 0;
  sm[threadIdx.x] = v;
  __syncthreads();
  for (int off = 1; off < 256; off <<= 1) {
    int t = (threadIdx.x >= (unsigned)off) ? sm[threadIdx.x - off] : 0;
    __syncthreads();
    sm[threadIdx.x] += t;
    __syncthreads();
  }
  if (threadIdx.x < nb) part[threadIdx.x] = sm[threadIdx.x] - v;  // exclusive
}
__global__ __launch_bounds__(256) void k_scan_fill(const int* __restrict__ deg,
    const int* __restrict__ part, int* __restrict__ rowptr) {
  __shared__ int sm[256];
  int i = blockIdx.x * 256 + threadIdx.x;
  int v = (i < NN) ? deg[i] : 0;
  sm[threadIdx.x] = v;
  __syncthreads();
  for (int off = 1; off < 256; off <<= 1) {
    int t = (threadIdx.x >= (unsigned)off) ? sm[threadIdx.x - off] : 0;
    __syncthreads();
    sm[threadIdx.x] += t;
    __syncthreads();
  }
  if (i <= NN) rowptr[i] = part[blockIdx.x] + sm[threadIdx.x] - v;
}
__global__ __launch_bounds__(256) void k_copy(const int* __restrict__ a, int* __restrict__ b) {
  int i = blockIdx.x * 256 + threadIdx.x;
  if (i < NN) b[i] = a[i];
}
__global__ __launch_bounds__(256) void k_fill(const int* __restrict__ dst,
    int* __restrict__ cursor, int* __restrict__ eids) {
  int eid = blockIdx.x * 256 + threadIdx.x;
  if (eid >= NE) return;
  int pos = atomicAdd(&cursor[dst[eid]], 1);
  eids[pos] = eid;
}

// ---------------- gather-sum agg ----------------
__global__ __launch_bounds__(256) void k_gather(const float* __restrict__ h,
    const float* __restrict__ e, const int* __restrict__ rowptr,
    const int* __restrict__ eids, const int* __restrict__ src, float* __restrict__ agg) {
  int slot = threadIdx.x >> 2, sub = threadIdx.x & 3;
  int n = blockIdx.x * 64 + slot;
  if (n >= NN) return;
  int r0 = rowptr[n], r1 = rowptr[n + 1];
  float4 acc[7];
  #pragma unroll
  for (int i = 0; i < 7; ++i) { acc[i].x = 0.f; acc[i].y = 0.f; acc[i].z = 0.f; acc[i].w = 0.f; }
  for (int p = r0; p < r1; ++p) {
    int s = src[eids[p]];
    const float4* hp = (const float4*)&h[(size_t)s * HD];
    const float4* ep = (const float4*)&e[(size_t)p * HD];
    #pragma unroll
    for (int i = 0; i < 7; ++i) {
      int c = sub + i * 4;
      if (c < 25) {
        float4 hv = hp[c], ev = ep[c];
        acc[i].x += frelu(hv.x + ev.x);
        acc[i].y += frelu(hv.y + ev.y);
        acc[i].z += frelu(hv.z + ev.z);
        acc[i].w += frelu(hv.w + ev.w);
      }
    }
  }
  float4* ap = (float4*)&agg[(size_t)n * HD];
  #pragma unroll
  for (int i = 0; i < 7; ++i) {
    int c = sub + i * 4;
    if (c < 25) ap[c] = acc[i];
  }
}

// fp32 node update (accuracy-critical path)
__global__ __launch_bounds__(256) void k_node_update(float* __restrict__ h,
    const float* __restrict__ agg,
    const float* __restrict__ w1, const float* __restrict__ b1,
    const float* __restrict__ w2, const float* __restrict__ b2,
    const float* __restrict__ gamma, const float* __restrict__ beta) {
  __shared__ float zs[64 * 101];
  int tid = threadIdx.x;
  int base = blockIdx.x * 64;
  for (int idx = tid; idx < 64 * HD; idx += 256) {
    int n = idx / HD, k = idx % HD;
    int gn = base + n; int cn = gn < NN ? gn : NN - 1;
    zs[n * 101 + k] = h[(size_t)cn * HD + k] + agg[(size_t)cn * HD + k];
  }
  __syncthreads();
  int el = tid & 63;
  int o0 = __builtin_amdgcn_readfirstlane((tid >> 6) * 25);
  float* row = &zs[el * 101];
  float acc[25];
  #pragma unroll
  for (int j = 0; j < 25; ++j) acc[j] = b1[o0 + j];
  for (int k = 0; k < HD; ++k) {
    float a = row[k];
    const float* wr = &w1[k * HD + o0];
    #pragma unroll
    for (int j = 0; j < 25; ++j) acc[j] = fmaf(a, wr[j], acc[j]);
  }
  __syncthreads();
  #pragma unroll
  for (int j = 0; j < 25; ++j) row[o0 + j] = frelu(acc[j]);
  __syncthreads();
  float acc2[25];
  #pragma unroll
  for (int j = 0; j < 25; ++j) acc2[j] = b2[o0 + j];
  for (int k = 0; k < HD; ++k) {
    float a = row[k];
    const float* wr = &w2[k * HD + o0];
    #pragma unroll
    for (int j = 0; j < 25; ++j) acc2[j] = fmaf(a, wr[j], acc2[j]);
  }
  int gn = base + el;
  if (gn < NN) {
    const float bninv = 0.99999500003749973f;  // 1/sqrt(1+1e-5)
    #pragma unroll
    for (int j = 0; j < 25; ++j) {
      int o = o0 + j;
      float bn = acc2[j] * (gamma[o] * bninv) + beta[o];
      h[(size_t)gn * HD + o] = (h[(size_t)gn * HD + o] + frelu(bn)) * 0.5f;
    }
  }
}

// ---- layer-1 edge update: weights LDS-resident, grid-stride tiles, inline-A ----
// 1 block/CU (LDS 117KB). Stage W once; 2 barriers/tile; no persistent A frags.
__global__ __launch_bounds__(256) void k_edge_mfma(
    const float* __restrict__ h, float* __restrict__ e,
    const int* __restrict__ eids, const int* __restrict__ src, const int* __restrict__ dst,
    const unsigned short* __restrict__ w1p, const float* __restrict__ b1,
    const unsigned short* __restrict__ w2p, const float* __restrict__ b2) {
  __shared__ __align__(16) char lds[116736];
  char* W1L = lds;             // 71680 = 10 panels x 448 uint4
  char* W2L = lds + 71680;     // 28672 = 4 panels
  char* A2  = lds + 100352;    // 16384: GEMM2-A bf16 [64][128] swizzled
  int tid = threadIdx.x;
  for (int i = tid; i < 4480; i += 256) ((uint4*)W1L)[i] = ((const uint4*)w1p)[i];
  for (int i = tid; i < 1792; i += 256) ((uint4*)W2L)[i] = ((const uint4*)w2p)[i];
  __syncthreads();

  int lane = tid & 63, w = tid >> 6;
  int l15 = lane & 15, lq = lane >> 4;
  int arow = w * 16 + l15;
  f32x4 zero = {0.f, 0.f, 0.f, 0.f};

  for (int tile = blockIdx.x; tile < NT64; tile += gridDim.x) {
    int base = tile * 64;
    int p = base + arow;
    int eid = eids[p];
    const float* hs = h + (size_t)src[eid] * HD;
    const float* hd = h + (size_t)dst[eid] * HD;
    const float* ep = e + (size_t)p * HD;

    // -------- GEMM1: inline-A from global, W from LDS, no per-phase barriers --------
    f32x4 acc[7];
    #pragma unroll
    for (int nt = 0; nt < 7; ++nt) acc[nt] = zero;
    #pragma unroll
    for (int ks = 0; ks < 10; ++ks) {
      bf16x8 a = frag_a(ks, lq, hs, hd, ep);
      const char* wb = W1L + ks * 7168;
      #pragma unroll
      for (int nt = 0; nt < 7; ++nt) {
        bf16x8 b = *(const bf16x8*)(wb + (nt * 64 + lane) * 16);
        acc[nt] = __builtin_amdgcn_mfma_f32_16x16x32_bf16(a, b, acc[nt], 0, 0, 0);
      }
    }
    // ep1: relu(C1+b1) -> A2 bf16
    #pragma unroll
    for (int nt = 0; nt < 7; ++nt) {
      int o = nt * 16 + l15;
      float bias = (o < HD) ? b1[o] : 0.f;
      #pragma unroll
      for (int i = 0; i < 4; ++i) {
        int r = w * 16 + lq * 4 + i;
        float v = acc[nt][i] + bias;
        v = (o < HD) ? frelu(v) : 0.f;
        *(unsigned short*)(A2 + SWZ(r, r * 256 + o * 2)) = f2bf(v);
      }
    }
    for (int idx = tid; idx < 64 * 8; idx += 256) {
      int r = idx / 8, c = idx % 8;
      *(unsigned int*)(A2 + SWZ(r, r * 256 + 224 + c * 4)) = 0;
    }
    __syncthreads();
    // -------- GEMM2 --------
    f32x4 acc2[7];
    #pragma unroll
    for (int nt = 0; nt < 7; ++nt) acc2[nt] = zero;
    #pragma unroll
    for (int ks = 0; ks < 4; ++ks) {
      bf16x8 a = *(const bf16x8*)(A2 + SWZ(arow, arow * 256 + (ks * 32 + lq * 8) * 2));
      const char* wb = W2L + ks * 7168;
      #pragma unroll
      for (int nt = 0; nt < 7; ++nt) {
        bf16x8 b = *(const bf16x8*)(wb + (nt * 64 + lane) * 16);
        acc2[nt] = __builtin_amdgcn_mfma_f32_16x16x32_bf16(a, b, acc2[nt], 0, 0, 0);
      }
    }
    // ep2: e += 0.5*(C2+b2)
    #pragma unroll
    for (int nt = 0; nt < 7; ++nt) {
      int o = nt * 16 + l15;
      if (o < HD) {
        float bias = b2[o];
        #pragma unroll
        for (int i = 0; i < 4; ++i) {
          int r = w * 16 + lq * 4 + i;
          size_t pp = (size_t)(base + r) * HD + o;
          e[pp] = e[pp] + 0.5f * (acc2[nt][i] + bias);
        }
      }
    }
    __syncthreads();   // protect A2 before next tile's ep1
  }
}

// ---- layer-2 + final MLP fused: weights LDS-resident (W1,W2,tail), WF from global ----
__global__ __launch_bounds__(256) void k_edge_final_mfma(
    const float* __restrict__ h, const float* __restrict__ e,
    const int* __restrict__ eids, const int* __restrict__ src, const int* __restrict__ dst,
    const unsigned short* __restrict__ w1p, const float* __restrict__ b1,
    const unsigned short* __restrict__ w2p, const float* __restrict__ b2,
    const unsigned short* __restrict__ wf1p, const float* __restrict__ fb1,
    const float* __restrict__ fw2, const float* __restrict__ fb2,
    const float* __restrict__ fw3, const float* __restrict__ fb3,
    float* __restrict__ out) {
  __shared__ __align__(16) char lds[121940];
  char* W1L = lds;                       // 71680
  char* W2L = lds + 71680;               // 28672
  char* A2  = lds + 100352;              // 16384: GEMM2-A / e_new exchange / t fp32
  float* W2s = (float*)(lds + 116736);   // 1250
  float* b2s = (float*)(lds + 121736);   // 25
  float* W3s = (float*)(lds + 121836);   // 25
  float* b3s = (float*)(lds + 121936);   // 1
  int tid = threadIdx.x;
  for (int i = tid; i < 4480; i += 256) ((uint4*)W1L)[i] = ((const uint4*)w1p)[i];
  for (int i = tid; i < 1792; i += 256) ((uint4*)W2L)[i] = ((const uint4*)w2p)[i];
  for (int i = tid; i < 1250; i += 256) W2s[i] = fw2[i];
  if (tid < 25) { b2s[tid] = fb2[tid]; W3s[tid] = fw3[tid]; }
  if (tid == 0) b3s[0] = fb3[0];
  __syncthreads();

  int lane = tid & 63, w = tid >> 6;
  int l15 = lane & 15, lq = lane >> 4;
  int arow = w * 16 + l15;
  f32x4 zero = {0.f, 0.f, 0.f, 0.f};
  bf16x8 zz; zz[0]=0; zz[1]=0; zz[2]=0; zz[3]=0; zz[4]=0; zz[5]=0; zz[6]=0; zz[7]=0;

  for (int tile = blockIdx.x; tile < NT64; tile += gridDim.x) {
    int base = tile * 64;
    int p = base + arow;
    int eid = eids[p];
    const float* hs = h + (size_t)src[eid] * HD;
    const float* hd = h + (size_t)dst[eid] * HD;
    const float* ep = e + (size_t)p * HD;

    // -------- GEMM1 --------
    f32x4 acc[7];
    #pragma unroll
    for (int nt = 0; nt < 7; ++nt) acc[nt] = zero;
    #pragma unroll
    for (int ks = 0; ks < 10; ++ks) {
      bf16x8 a = frag_a(ks, lq, hs, hd, ep);
      const char* wb = W1L + ks * 7168;
      #pragma unroll
      for (int nt = 0; nt < 7; ++nt) {
        bf16x8 b = *(const bf16x8*)(wb + (nt * 64 + lane) * 16);
        acc[nt] = __builtin_amdgcn_mfma_f32_16x16x32_bf16(a, b, acc[nt], 0, 0, 0);
      }
    }
    // ep1: relu(C1+b1) -> A2 bf16
    #pragma unroll
    for (int nt = 0; nt < 7; ++nt) {
      int o = nt * 16 + l15;
      float bias = (o < HD) ? b1[o] : 0.f;
      #pragma unroll
      for (int i = 0; i < 4; ++i) {
        int r = w * 16 + lq * 4 + i;
        float v = acc[nt][i] + bias;
        v = (o < HD) ? frelu(v) : 0.f;
        *(unsigned short*)(A2 + SWZ(r, r * 256 + o * 2)) = f2bf(v);
      }
    }
    for (int idx = tid; idx < 64 * 8; idx += 256) {
      int r = idx / 8, c = idx % 8;
      *(unsigned int*)(A2 + SWZ(r, r * 256 + 224 + c * 4)) = 0;
    }
    __syncthreads();   // B1
    // -------- GEMM2 --------
    f32x4 acc2[7];
    #pragma unroll
    for (int nt = 0; nt < 7; ++nt) acc2[nt] = zero;
    #pragma unroll
    for (int ks = 0; ks < 4; ++ks) {
      bf16x8 a = *(const bf16x8*)(A2 + SWZ(arow, arow * 256 + (ks * 32 + lq * 8) * 2));
      const char* wb = W2L + ks * 7168;
      #pragma unroll
      for (int nt = 0; nt < 7; ++nt) {
        bf16x8 b = *(const bf16x8*)(wb + (nt * 64 + lane) * 16);
        acc2[nt] = __builtin_amdgcn_mfma_f32_16x16x32_bf16(a, b, acc2[nt], 0, 0, 0);
      }
    }
    // ep2: e_new = e + 0.5*(C2+b2) -> bf16 into A2 exchange
    #pragma unroll
    for (int nt = 0; nt < 7; ++nt) {
      int o = nt * 16 + l15;
      if (o < HD) {
        float bias = b2[o];
        #pragma unroll
        for (int i = 0; i < 4; ++i) {
          int r = w * 16 + lq * 4 + i;
          float ne = e[(size_t)(base + r) * HD + o] + 0.5f * (acc2[nt][i] + bias);
          *(unsigned short*)(A2 + SWZ(r, r * 256 + o * 2)) = f2bf(ne);
        }
      }
    }
    if (tid < 192) {   // zero exchange cols 100..111
      int r = tid / 3, j = tid % 3;
      *(uint2*)(A2 + SWZ(r, r * 256 + 200 + j * 8)) = (uint2){0u, 0u};
    }
    __syncthreads();   // B2
    // -------- GEMM3 (final L1): h inline-global, e_new from A2, W from global L2 --------
    f32x4 acc3[4];
    #pragma unroll
    for (int nt = 0; nt < 4; ++nt) acc3[nt] = zero;
    #pragma unroll
    for (int ks = 0; ks < 10; ++ks) {
      bf16x8 a;
      if (ks <= 2)      a = cvt8(L4(hs + ks * 32 + lq * 8), L4(hs + ks * 32 + lq * 8 + 4));
      else if (ks == 3) a = (lq == 0) ? cvt8(L4(hs + 96), L4(hd))
                                      : cvt8(L4(hd + lq * 8 - 4), L4(hd + lq * 8));
      else if (ks <= 5) a = cvt8(L4(hd + (ks - 3) * 32 - 4 + lq * 8),
                                 L4(hd + (ks - 3) * 32 + lq * 8));
      else if (ks == 6) a = (lq == 0) ? cvt8(L4(hd + 92), L4(hd + 96))
                          : *(const bf16x8*)(A2 + SWZ(arow, arow * 256 + (lq * 8 - 8) * 2));
      else if (ks <= 8) a = *(const bf16x8*)(A2 + SWZ(arow, arow * 256 + ((ks - 7) * 32 + 24 + lq * 8) * 2));
      else              a = (lq == 0) ? *(const bf16x8*)(A2 + SWZ(arow, arow * 256 + 88 * 2))
                          : (lq == 1) ? *(const bf16x8*)(A2 + SWZ(arow, arow * 256 + 96 * 2))
                                      : zz;
      #pragma unroll
      for (int nt = 0; nt < 4; ++nt) {
        bf16x8 b = *(const bf16x8*)(wf1p + ((size_t)(ks * 4 + nt) * 64 + lane) * 8);
        acc3[nt] = __builtin_amdgcn_mfma_f32_16x16x32_bf16(a, b, acc3[nt], 0, 0, 0);
      }
    }
    __syncthreads();   // B3: A2 e-frag reads done before t-writes
    // t = relu(C3+fb1) fp32 [64][52] stride 208 in A2 region
    #pragma unroll
    for (int nt = 0; nt < 4; ++nt) {
      int o = nt * 16 + l15;
      if (o < 50) {
        float bias = fb1[o];
        #pragma unroll
        for (int i = 0; i < 4; ++i) {
          int r = w * 16 + lq * 4 + i;
          *(float*)(A2 + r * 208 + o * 4) = frelu(acc3[nt][i] + bias);
        }
      }
    }
    __syncthreads();   // B4
    // fp32 tail: per-wave, 4 lanes per edge, 50->25->1
    {
      int elg = w * 16 + (lane >> 2), q4 = lane & 3;
      const float* trow = (const float*)(A2 + elg * 208);
      float s[7];
      {
        int i = 0;
        #pragma unroll
        for (int j0 = 0; j0 < 25; j0 += 4) { if (j0 + q4 < 25) s[i++] = b2s[j0 + q4]; }
      }
      for (int k = 0; k < 50; ++k) {
        float tv = trow[k];
        int i = 0;
        #pragma unroll
        for (int j0 = 0; j0 < 25; j0 += 4) {
          if (j0 + q4 < 25) { s[i] = fmaf(tv, W2s[k * 25 + j0 + q4], s[i]); ++i; }
        }
      }
      float racc = 0.f;
      {
        int i = 0;
        #pragma unroll
        for (int j0 = 0; j0 < 25; j0 += 4) {
          if (j0 + q4 < 25) { racc = fmaf(frelu(s[i]), W3s[j0 + q4], racc); ++i; }
        }
      }
      racc += __shfl_xor(racc, 1, 4);
      racc += __shfl_xor(racc, 2, 4);
      if (q4 == 0) out[eids[base + elg]] = racc + b3s[0];
    }
    __syncthreads();   // B5: tail reads done before next tile's ep1
  }
}

extern "C" void kernel_launch(void* const* d_in, const int* in_sizes, int n_in,
                              void* d_out, int out_size, void* d_ws, size_t ws_size,
                              hipStream_t stream) {
  (void)in_sizes; (void)n_in; (void)out_size; (void)ws_size;
  const float* x       = (const float*)d_in[0];
  const int*   eidx    = (const int*)  d_in[1];
  const float* eattr   = (const float*)d_in[2];
  const float* node_w  = (const float*)d_in[3];
  const float* node_b  = (const float*)d_in[4];
  const float* edge_w  = (const float*)d_in[5];
  const float* edge_b  = (const float*)d_in[6];
  const float* conv_w1 = (const float*)d_in[7];
  const float* conv_b1 = (const float*)d_in[8];
  const float* conv_w2 = (const float*)d_in[9];
  const float* conv_b2 = (const float*)d_in[10];
  const float* bn_g    = (const float*)d_in[11];
  const float* bn_b    = (const float*)d_in[12];
  const float* em_w1   = (const float*)d_in[13];
  const float* em_b1   = (const float*)d_in[14];
  const float* em_w2   = (const float*)d_in[15];
  const float* em_b2   = (const float*)d_in[16];
  const float* mlp_w1  = (const float*)d_in[17];
  const float* mlp_b1  = (const float*)d_in[18];
  const float* mlp_w2  = (const float*)d_in[19];
  const float* mlp_b2  = (const float*)d_in[20];
  const float* mlp_w3  = (const float*)d_in[21];
  const float* mlp_b3  = (const float*)d_in[22];

  const int* src = eidx;
  const int* dst = eidx + NE;

  // ws layout (max 202.15 MB; proven in rounds 5-8)
  char* ws = (char*)d_ws;
  float* h    = (float*)(ws);                     // 20,000,000
  float* agg  = (float*)(ws + 20000000);          // 20,000,000
  float* e    = (float*)(ws + 40000000);          // 160,000,000 (PERMUTED rows)
  unsigned short* w1p  = (unsigned short*)(ws + 200000000);  // 71,680
  unsigned short* w2p  = (unsigned short*)(ws + 200071680);  // 28,672
  unsigned short* wf1p = (unsigned short*)(ws + 200100352);  // 40,960
  int* rowptr = (int*)(ws + 200141312);           // 50,001 ints (+pad)
  int* cursor = (int*)(ws + 200341504);           // 50,000 ints
  int* eids   = (int*)(ws + 200541504);           // 400,000 ints
  int* part   = (int*)(ws + 202141504);           // 256 ints

  const int SCAN_NB = (NN + 256) / 256;
  // CSR build (dst-sorted permutation)
  hipMemsetAsync(cursor, 0, (size_t)NN * 4, stream);
  k_hist<<<(NE + 255) / 256, 256, 0, stream>>>(dst, cursor);
  k_scan_part<<<SCAN_NB, 256, 0, stream>>>(cursor, part);
  k_scan_top<<<1, 256, 0, stream>>>(part, SCAN_NB);
  k_scan_fill<<<SCAN_NB, 256, 0, stream>>>(cursor, part, rowptr);
  k_copy<<<SCAN_NB, 256, 0, stream>>>(rowptr, cursor);
  k_fill<<<(NE + 255) / 256, 256, 0, stream>>>(dst, cursor, eids);

  k_node_embed<<<(NN * HD + 255) / 256, 256, 0, stream>>>(x, node_w, node_b, h);
  {
    long long th = (long long)NE * 25;
    k_edge_embed_perm<<<(unsigned)((th + 255) / 256), 256, 0, stream>>>(eattr, eids, edge_w, edge_b, e);
  }

  k_pack<<<(10 * 4 * 64 + 255) / 256, 256, 0, stream>>>(mlp_w1, wf1p, 300, 50, 10, 4);

  for (int i = 0; i < 2; ++i) {
    k_gather<<<(NN + 63) / 64, 256, 0, stream>>>(h, e, rowptr, eids, src, agg);
    k_node_update<<<(NN + 63) / 64, 256, 0, stream>>>(
        h, agg, conv_w1 + i * HD * HD, conv_b1 + i * HD,
        conv_w2 + i * HD * HD, conv_b2 + i * HD, bn_g + i * HD, bn_b + i * HD);
    k_pack<<<(10 * 7 * 64 + 255) / 256, 256, 0, stream>>>(em_w1 + i * 30000, w1p, 300, 100, 10, 7);
    k_pack<<<(4 * 7 * 64 + 255) / 256, 256, 0, stream>>>(em_w2 + i * 10000,  w2p, 100, 100, 4, 7);
    if (i == 0) {
      k_edge_mfma<<<256, 256, 0, stream>>>(
          h, e, eids, src, dst, w1p, em_b1, w2p, em_b2);
    } else {
      k_edge_final_mfma<<<256, 256, 0, stream>>>(
          h, e, eids, src, dst, w1p, em_b1 + HD, w2p, em_b2 + HD,
          wf1p, mlp_b1, mlp_w2, mlp_b2, mlp_w3, mlp_b3, (float*)d_out);
    }
  }
}